// Round 6
// baseline (552.882 us; speedup 1.0000x reference)
//
#include <hip/hip_runtime.h>
#include <math.h>

#define F 128
#define HEADS 4
#define HD 32

// ---------------- CSR build ----------------
__global__ void hist_kernel(const int* __restrict__ tgt, int* __restrict__ cnt, int E) {
    int i = blockIdx.x * blockDim.x + threadIdx.x;
    if (i < E) atomicAdd(&cnt[tgt[i]], 1);
}

// single-block exclusive scan over N entries -> row_off[N+1]; also copies to next_ (atomic cursors)
__global__ void scan_kernel(const int* __restrict__ cnt, int* __restrict__ row_off,
                            int* __restrict__ next_, int N) {
    __shared__ int wsum[16];
    __shared__ int carry_s;
    int t = threadIdx.x;            // 1024 threads
    int lane = t & 63, wid = t >> 6;
    if (t == 0) carry_s = 0;
    __syncthreads();
    for (int base = 0; base < N; base += 1024) {
        int i = base + t;
        int v = (i < N) ? cnt[i] : 0;
        int incl = v;
        for (int d = 1; d < 64; d <<= 1) {
            int n = __shfl_up(incl, d);
            if (lane >= d) incl += n;
        }
        if (lane == 63) wsum[wid] = incl;
        __syncthreads();
        if (wid == 0) {
            int ws = (lane < 16) ? wsum[lane] : 0;
            for (int d = 1; d < 16; d <<= 1) {
                int n = __shfl_up(ws, d);
                if (lane >= d) ws += n;
            }
            if (lane < 16) wsum[lane] = ws;
        }
        __syncthreads();
        int carry = carry_s;
        int waveoff = (wid > 0) ? wsum[wid - 1] : 0;
        int excl = carry + waveoff + incl - v;
        if (i < N) { row_off[i] = excl; next_[i] = excl; }
        __syncthreads();
        if (t == 1023) carry_s = carry + wsum[15];
        __syncthreads();
    }
    if (t == 0) row_off[N] = carry_s;
}

__global__ void scatter_kernel(const int* __restrict__ src, const int* __restrict__ tgt,
                               int* __restrict__ next_, int* __restrict__ csr_src, int E) {
    int i = blockIdx.x * blockDim.x + threadIdx.x;
    if (i < E) {
        int tg = tgt[i];
        int pos = atomicAdd(&next_[tg], 1);
        csr_src[pos] = src[i];
    }
}

// ---------------- shared GEMM body: out[n][c] = sum_f x[n][f]*Wl[f][c] + b[c] ----------------
// Wl staged in LDS with padded stride 129 (bank-conflict-free for both staging and compute).
__device__ __forceinline__ void gemm_body(const float* __restrict__ x, const float* __restrict__ b,
                                          float* __restrict__ out, int N,
                                          const float* Wl, float* Xl) {
    int t = threadIdx.x;
    int o = t & 31;         // output column group base
    int nl = t >> 5;        // 0..7 node-local
    float bb[4];
#pragma unroll
    for (int j = 0; j < 4; j++) bb[j] = b[o + 32 * j];
    for (int nb = blockIdx.x * 16; nb < N; nb += gridDim.x * 16) {
        // stage 16 x-rows
        for (int idx = t; idx < 2048; idx += 256) {
            int n = nb + (idx >> 7);
            Xl[idx] = (n < N) ? x[(size_t)n * F + (idx & 127)] : 0.f;
        }
        __syncthreads();
        float acc0[4], acc1[4];
#pragma unroll
        for (int j = 0; j < 4; j++) { acc0[j] = bb[j]; acc1[j] = bb[j]; }
#pragma unroll 4
        for (int f = 0; f < 128; f++) {
            float xa = Xl[nl * 128 + f];
            float xb = Xl[(nl + 8) * 128 + f];
#pragma unroll
            for (int j = 0; j < 4; j++) {
                float wv = Wl[f * 129 + o + 32 * j];
                acc0[j] += xa * wv;
                acc1[j] += xb * wv;
            }
        }
        int n0 = nb + nl, n1 = nb + nl + 8;
        if (n0 < N) {
#pragma unroll
            for (int j = 0; j < 4; j++) out[(size_t)n0 * F + o + 32 * j] = acc0[j];
        }
        if (n1 < N) {
#pragma unroll
            for (int j = 0; j < 4; j++) out[(size_t)n1 * F + o + 32 * j] = acc1[j];
        }
        __syncthreads();
    }
}

// QKV: weight layout w[h][f][d] -> column c = h*32+d
__global__ __launch_bounds__(256, 2) void qkv_kernel(
    const float* __restrict__ x,
    const float* __restrict__ wq, const float* __restrict__ bq,
    const float* __restrict__ wk, const float* __restrict__ bk,
    const float* __restrict__ wv, const float* __restrict__ bv,
    float* __restrict__ qo, float* __restrict__ ko, float* __restrict__ vo, int N) {
    __shared__ float Wl[128 * 129];
    __shared__ float Xl[2048];
    const float* w = blockIdx.y == 0 ? wq : (blockIdx.y == 1 ? wk : wv);
    const float* b = blockIdx.y == 0 ? bq : (blockIdx.y == 1 ? bk : bv);
    float* out = blockIdx.y == 0 ? qo : (blockIdx.y == 1 ? ko : vo);
    int t = threadIdx.x;
    for (int idx = t; idx < 16384; idx += 256) {
        int h = idx >> 12, f = (idx >> 5) & 127, d = idx & 31;
        Wl[f * 129 + h * 32 + d] = w[idx];
    }
    __syncthreads();
    gemm_body(x, b, out, N, Wl, Xl);
}

// Final: out = agg @ wo^T + bo ; wo layout [o][f]
__global__ __launch_bounds__(256, 2) void outproj_kernel(
    const float* __restrict__ aggin, const float* __restrict__ wo,
    const float* __restrict__ bo, float* __restrict__ out, int N) {
    __shared__ float Wl[128 * 129];
    __shared__ float Xl[2048];
    int t = threadIdx.x;
    for (int idx = t; idx < 16384; idx += 256) {
        int c = idx >> 7, f = idx & 127;     // wo[c][f] -> Wl[f][c]
        Wl[f * 129 + c] = wo[idx];
    }
    __syncthreads();
    gemm_body(aggin, bo, out, N, Wl, Xl);
}

// ---------------- fused per-node edge attention ----------------
// One wave per target node; online softmax; writes normalized aggregate.
//
// Lane-mapping invariant (do not break):
//   score phase: lane = slot*4 + h4; (slot,h4) computes the partial dot of
//     edge slot `slot` for head `h4` over dims {i*16+h4*4..+3 : i=0..7 of head i>>1};
//     xor-1/2 completes each head's 32-dim dot; lane's own head score = sacc[h4].
//   chunk stats: after xor-4/8/16/32 reduce over slots, lane h (h<4, i.e. slot 0)
//     holds head h's chunk max / exp-sum -> broadcast via __shfl(. , hagg).
//   agg phase: lane owns output dims {2*lane, 2*lane+1}; head of dim 2*lane is
//     (2*lane)/32 == lane>>4 == hagg; edge j's p for head hagg lives in lane
//     (j<<2)|hagg; edge j's srcn lives in lane j<<2.
__global__ __launch_bounds__(256) void edge_attn_kernel(
    const float* __restrict__ q, const float* __restrict__ k, const float* __restrict__ v,
    const int* __restrict__ row_off, const int* __restrict__ csr_src,
    float* __restrict__ agg, int N) {
    int wave = (blockIdx.x * blockDim.x + threadIdx.x) >> 6;
    if (wave >= N) return;          // uniform per wave
    int lane = threadIdx.x & 63;
    int n = wave;
    int h4 = lane & 3;              // score-phase head (lane = slot*4 + h4)
    int slot = lane >> 2;           // 0..15 edge slot
    int hagg = lane >> 4;           // aggregation-phase head

    // q fragment: instruction i covers words i*16 + h4*4 .. +3 ; head of block i is i>>1
    float4 qf[8];
#pragma unroll
    for (int i = 0; i < 8; i++)
        qf[i] = *(const float4*)&q[(size_t)n * F + i * 16 + h4 * 4];

    int base = row_off[n];
    int deg = row_off[n + 1] - base;

    float m_sc = -INFINITY;   // running max for head h4   (score lanes)
    float m_ag = -INFINITY;   // running max for head hagg (agg lanes)
    float den = 0.f;
    float2 accA = make_float2(0.f, 0.f);   // even slots
    float2 accB = make_float2(0.f, 0.f);   // odd slots

    for (int c0 = 0; c0 < deg; c0 += 16) {
        int rem = deg - c0;
        int nj = rem < 16 ? rem : 16;
        int mye = c0 + slot;
        int srcn = (mye < deg) ? csr_src[base + mye] : 0;

        float sacc[4] = {0.f, 0.f, 0.f, 0.f};
#pragma unroll
        for (int i = 0; i < 8; i++) {
            float4 kk = *(const float4*)&k[(size_t)srcn * F + i * 16 + h4 * 4];
            sacc[i >> 1] += qf[i].x * kk.x + qf[i].y * kk.y + qf[i].z * kk.z + qf[i].w * kk.w;
        }
        // combine element subsets across the 4 lanes of this slot
#pragma unroll
        for (int hh = 0; hh < 4; hh++) {
            sacc[hh] += __shfl_xor(sacc[hh], 1);
            sacc[hh] += __shfl_xor(sacc[hh], 2);
        }
        float s = h4 == 0 ? sacc[0] : h4 == 1 ? sacc[1] : h4 == 2 ? sacc[2] : sacc[3];
        if (mye >= deg) s = -INFINITY;

        // chunk max per head (reduce over slots)
        float cm = s;
        cm = fmaxf(cm, __shfl_xor(cm, 4));
        cm = fmaxf(cm, __shfl_xor(cm, 8));
        cm = fmaxf(cm, __shfl_xor(cm, 16));
        cm = fmaxf(cm, __shfl_xor(cm, 32));

        float nm_sc = fmaxf(m_sc, cm);
        float cm_ag = __shfl(cm, hagg);       // lane 'hagg' holds head hagg's chunk max
        float nm_ag = fmaxf(m_ag, cm_ag);

        float p = __expf(s - nm_sc);          // 0 for padded slots
        float psum = p;
        psum += __shfl_xor(psum, 4);
        psum += __shfl_xor(psum, 8);
        psum += __shfl_xor(psum, 16);
        psum += __shfl_xor(psum, 32);

        float scale = __expf(m_ag - nm_ag);   // first chunk: exp(-inf)=0, safe
        den = den * scale + __shfl(psum, hagg);
        accA.x *= scale; accA.y *= scale;
        accB.x *= scale; accB.y *= scale;

#pragma unroll 4
        for (int j = 0; j < nj; j++) {
            float pj = __shfl(p, (j << 2) | hagg);
            int sj = __shfl(srcn, j << 2);
            float2 v2 = *(const float2*)&v[(size_t)sj * F + lane * 2];
            if (j & 1) { accB.x += pj * v2.x; accB.y += pj * v2.y; }
            else       { accA.x += pj * v2.x; accA.y += pj * v2.y; }
        }
        m_sc = nm_sc;
        m_ag = nm_ag;
    }
    float inv = (den > 0.f) ? 1.f / den : 0.f;   // deg==0 -> zeros (ref: agg=0, out=bo)
    *(float2*)&agg[(size_t)n * F + lane * 2] =
        make_float2((accA.x + accB.x) * inv, (accA.y + accB.y) * inv);
}

// ---------------- launch ----------------
extern "C" void kernel_launch(void* const* d_in, const int* in_sizes, int n_in,
                              void* d_out, int out_size, void* d_ws, size_t ws_size,
                              hipStream_t stream) {
    const float* x  = (const float*)d_in[0];
    const int*   ei = (const int*)d_in[1];
    const float* wq = (const float*)d_in[2];
    const float* bq = (const float*)d_in[3];
    const float* wk = (const float*)d_in[4];
    const float* bk = (const float*)d_in[5];
    const float* wv = (const float*)d_in[6];
    const float* bv = (const float*)d_in[7];
    const float* wo = (const float*)d_in[8];
    const float* bo = (const float*)d_in[9];
    float* out = (float*)d_out;

    int N = in_sizes[0] / F;
    int E = in_sizes[1] / 2;
    const int* srcs = ei;
    const int* tgts = ei + E;

    // Workspace budget check — if d_ws is smaller than we need, launching would
    // write out of bounds and can wedge the device (container death). Refuse
    // instead: validation fails cleanly and the bench harness survives.
    size_t need = (size_t)N * F * 4 * 4        // q, k, v, agg
                + (size_t)(N + 1) * 4          // row_off
                + (size_t)N * 4 * 2            // next_, cnt
                + (size_t)E * 4;               // csr_src
    if (ws_size < need) return;

    char* wsp = (char*)d_ws;
    float* q   = (float*)wsp; wsp += (size_t)N * F * 4;
    float* k   = (float*)wsp; wsp += (size_t)N * F * 4;
    float* v   = (float*)wsp; wsp += (size_t)N * F * 4;
    float* agg = (float*)wsp; wsp += (size_t)N * F * 4;
    int* row_off = (int*)wsp; wsp += (size_t)(N + 1) * 4;
    int* next_   = (int*)wsp; wsp += (size_t)N * 4;
    int* cnt     = (int*)wsp; wsp += (size_t)N * 4;
    int* csr_src = (int*)wsp; wsp += (size_t)E * 4;

    hipMemsetAsync(cnt, 0, (size_t)N * 4, stream);
    hist_kernel<<<(E + 255) / 256, 256, 0, stream>>>(tgts, cnt, E);
    scan_kernel<<<1, 1024, 0, stream>>>(cnt, row_off, next_, N);
    scatter_kernel<<<(E + 255) / 256, 256, 0, stream>>>(srcs, tgts, next_, csr_src, E);
    qkv_kernel<<<dim3(512, 3), 256, 0, stream>>>(x, wq, bq, wk, bk, wv, bv, q, k, v, N);
    edge_attn_kernel<<<(N + 3) / 4, 256, 0, stream>>>(q, k, v, row_off, csr_src, agg, N);
    outproj_kernel<<<512, 256, 0, stream>>>(agg, wo, bo, out, N);
}

// Round 8
// 532.355 us; speedup vs baseline: 1.0386x; 1.0386x over previous
//
#include <hip/hip_runtime.h>
#include <math.h>

#define F 128
#define HEADS 4
#define HD 32

// ---------------- CSR build ----------------
__global__ void hist_kernel(const int* __restrict__ tgt, int* __restrict__ cnt, int E) {
    int i = blockIdx.x * blockDim.x + threadIdx.x;
    if (i < E) atomicAdd(&cnt[tgt[i]], 1);
}

// single-block exclusive scan over N entries -> row_off[N+1]; also copies to next_ (atomic cursors)
__global__ void scan_kernel(const int* __restrict__ cnt, int* __restrict__ row_off,
                            int* __restrict__ next_, int N) {
    __shared__ int wsum[16];
    __shared__ int carry_s;
    int t = threadIdx.x;            // 1024 threads
    int lane = t & 63, wid = t >> 6;
    if (t == 0) carry_s = 0;
    __syncthreads();
    for (int base = 0; base < N; base += 1024) {
        int i = base + t;
        int v = (i < N) ? cnt[i] : 0;
        int incl = v;
        for (int d = 1; d < 64; d <<= 1) {
            int n = __shfl_up(incl, d);
            if (lane >= d) incl += n;
        }
        if (lane == 63) wsum[wid] = incl;
        __syncthreads();
        if (wid == 0) {
            int ws = (lane < 16) ? wsum[lane] : 0;
            for (int d = 1; d < 16; d <<= 1) {
                int n = __shfl_up(ws, d);
                if (lane >= d) ws += n;
            }
            if (lane < 16) wsum[lane] = ws;
        }
        __syncthreads();
        int carry = carry_s;
        int waveoff = (wid > 0) ? wsum[wid - 1] : 0;
        int excl = carry + waveoff + incl - v;
        if (i < N) { row_off[i] = excl; next_[i] = excl; }
        __syncthreads();
        if (t == 1023) carry_s = carry + wsum[15];
        __syncthreads();
    }
    if (t == 0) row_off[N] = carry_s;
}

__global__ void scatter_kernel(const int* __restrict__ src, const int* __restrict__ tgt,
                               int* __restrict__ next_, int* __restrict__ csr_src, int E) {
    int i = blockIdx.x * blockDim.x + threadIdx.x;
    if (i < E) {
        int tg = tgt[i];
        int pos = atomicAdd(&next_[tg], 1);
        csr_src[pos] = src[i];
    }
}

// ---------------- shared GEMM body: out[n][c] = sum_f x[n][f]*Wl[f][c] + b[c] ----------------
// Wl: [128][128] f-major, UNPADDED. W reads: wave-uniform f, lanes spread over
// 16B groups -> 64 lanes x b128 touch every bank exactly 8x = aggregate
// conflict-free (minimum cycles for b128). Xl reads: 2 distinct addrs/wave,
// 512B apart -> 2-way same-bank, free (m136). 32-node tile, thread = 4 nodes
// x 4 contiguous cols. Per 4-f step: 4 b128 W + 4 b128 X + 64 FMAs.
__device__ __forceinline__ void gemm_body(const float* __restrict__ x, const float* __restrict__ b,
                                          float* __restrict__ out, int N,
                                          const float* Wl, float* Xl) {
    int t = threadIdx.x;
    int c4 = t & 31;         // cols 4*c4 .. 4*c4+3
    int nl = t >> 5;         // 0..7 ; nodes nl, nl+8, nl+16, nl+24
    float4 bb = *(const float4*)&b[4 * c4];
    for (int nb = blockIdx.x * 32; nb < N; nb += gridDim.x * 32) {
        // stage 32 x-rows (float4 granularity; 1024 float4s, 4 per thread)
#pragma unroll
        for (int r = 0; r < 4; r++) {
            int idx = t + 256 * r;
            int node = idx >> 5, f4 = idx & 31;
            int gn = nb + node;
            float4 xv = (gn < N) ? *(const float4*)&x[(size_t)gn * F + 4 * f4]
                                 : make_float4(0.f, 0.f, 0.f, 0.f);
            *(float4*)&Xl[node * F + 4 * f4] = xv;
        }
        __syncthreads();
        float4 acc[4];
#pragma unroll
        for (int j = 0; j < 4; j++) acc[j] = bb;
#pragma unroll 2
        for (int f = 0; f < 128; f += 4) {
            float4 w0 = *(const float4*)&Wl[(f + 0) * F + 4 * c4];
            float4 w1 = *(const float4*)&Wl[(f + 1) * F + 4 * c4];
            float4 w2 = *(const float4*)&Wl[(f + 2) * F + 4 * c4];
            float4 w3 = *(const float4*)&Wl[(f + 3) * F + 4 * c4];
#pragma unroll
            for (int j = 0; j < 4; j++) {
                float4 xv = *(const float4*)&Xl[(nl + 8 * j) * F + f];
                acc[j].x += xv.x * w0.x + xv.y * w1.x + xv.z * w2.x + xv.w * w3.x;
                acc[j].y += xv.x * w0.y + xv.y * w1.y + xv.z * w2.y + xv.w * w3.y;
                acc[j].z += xv.x * w0.z + xv.y * w1.z + xv.z * w2.z + xv.w * w3.z;
                acc[j].w += xv.x * w0.w + xv.y * w1.w + xv.z * w2.w + xv.w * w3.w;
            }
        }
#pragma unroll
        for (int j = 0; j < 4; j++) {
            int gn = nb + nl + 8 * j;
            if (gn < N) *(float4*)&out[(size_t)gn * F + 4 * c4] = acc[j];
        }
        __syncthreads();
    }
}

// QKV: weight layout w[h][f][d] -> column c = h*32+d. Staging: thread t owns
// dst col-group c4 = t&31 (h = c4>>3, d4 = c4&7) and rows f = (t>>5)+8r.
__global__ __launch_bounds__(256, 2) void qkv_kernel(
    const float* __restrict__ x,
    const float* __restrict__ wq, const float* __restrict__ bq,
    const float* __restrict__ wk, const float* __restrict__ bk,
    const float* __restrict__ wv, const float* __restrict__ bv,
    float* __restrict__ qo, float* __restrict__ ko, float* __restrict__ vo, int N) {
    __shared__ float Wl[128 * 128];
    __shared__ float Xl[32 * 128];
    const float* w = blockIdx.y == 0 ? wq : (blockIdx.y == 1 ? wk : wv);
    const float* b = blockIdx.y == 0 ? bq : (blockIdx.y == 1 ? bk : bv);
    float* out = blockIdx.y == 0 ? qo : (blockIdx.y == 1 ? ko : vo);
    int t = threadIdx.x;
    int c4 = t & 31, h = c4 >> 3, d4 = c4 & 7;
    const float4* w4 = (const float4*)w;
#pragma unroll
    for (int r = 0; r < 16; r++) {
        int f = (t >> 5) + 8 * r;
        float4 wv4 = w4[h * 1024 + f * 8 + d4];   // w[h][f][4*d4..+3]
        *(float4*)&Wl[f * F + 4 * c4] = wv4;
    }
    __syncthreads();
    gemm_body(x, b, out, N, Wl, Xl);
}

// Final: out = agg @ wo^T + bo ; wo layout [o][f]. Transpose during staging via
// strided global gather (wo is L2-resident): thread t owns dst cols 4*c4..+3,
// rows f = (t>>5)+8r; reads wo[4*c4+e][f] scalars.
__global__ __launch_bounds__(256, 2) void outproj_kernel(
    const float* __restrict__ aggin, const float* __restrict__ wo,
    const float* __restrict__ bo, float* __restrict__ out, int N) {
    __shared__ float Wl[128 * 128];
    __shared__ float Xl[32 * 128];
    int t = threadIdx.x;
    int c4 = t & 31;
#pragma unroll
    for (int r = 0; r < 16; r++) {
        int f = (t >> 5) + 8 * r;
        float4 wv4;
        wv4.x = wo[(size_t)(4 * c4 + 0) * F + f];
        wv4.y = wo[(size_t)(4 * c4 + 1) * F + f];
        wv4.z = wo[(size_t)(4 * c4 + 2) * F + f];
        wv4.w = wo[(size_t)(4 * c4 + 3) * F + f];
        *(float4*)&Wl[f * F + 4 * c4] = wv4;
    }
    __syncthreads();
    gemm_body(aggin, bo, out, N, Wl, Xl);
}

// ---------------- fused per-node edge attention ----------------
// One wave per target node; online softmax; writes normalized aggregate.
//
// Lane-mapping invariant (do not break):
//   score phase: lane = slot*4 + h4; (slot,h4) computes the partial dot of
//     edge slot `slot` for head `h4` over dims {i*16+h4*4..+3 : i=0..7 of head i>>1};
//     xor-1/2 completes each head's 32-dim dot; lane's own head score = sacc[h4].
//   chunk stats: after xor-4/8/16/32 reduce over slots, lane h (h<4, i.e. slot 0)
//     holds head h's chunk max / exp-sum -> broadcast via __shfl(. , hagg).
//   agg phase: lane owns output dims {2*lane, 2*lane+1}; head of dim 2*lane is
//     (2*lane)/32 == lane>>4 == hagg; edge j's p for head hagg lives in lane
//     (j<<2)|hagg; edge j's srcn lives in lane j<<2.
__global__ __launch_bounds__(256) void edge_attn_kernel(
    const float* __restrict__ q, const float* __restrict__ k, const float* __restrict__ v,
    const int* __restrict__ row_off, const int* __restrict__ csr_src,
    float* __restrict__ agg, int N) {
    int wave = (blockIdx.x * blockDim.x + threadIdx.x) >> 6;
    if (wave >= N) return;          // uniform per wave
    int lane = threadIdx.x & 63;
    int n = wave;
    int h4 = lane & 3;              // score-phase head (lane = slot*4 + h4)
    int slot = lane >> 2;           // 0..15 edge slot
    int hagg = lane >> 4;           // aggregation-phase head

    // q fragment: instruction i covers words i*16 + h4*4 .. +3 ; head of block i is i>>1
    float4 qf[8];
#pragma unroll
    for (int i = 0; i < 8; i++)
        qf[i] = *(const float4*)&q[(size_t)n * F + i * 16 + h4 * 4];

    int base = row_off[n];
    int deg = row_off[n + 1] - base;

    float m_sc = -INFINITY;   // running max for head h4   (score lanes)
    float m_ag = -INFINITY;   // running max for head hagg (agg lanes)
    float den = 0.f;
    float2 accA = make_float2(0.f, 0.f);   // even slots
    float2 accB = make_float2(0.f, 0.f);   // odd slots

    for (int c0 = 0; c0 < deg; c0 += 16) {
        int rem = deg - c0;
        int nj = rem < 16 ? rem : 16;
        int mye = c0 + slot;
        int srcn = (mye < deg) ? csr_src[base + mye] : 0;

        float sacc[4] = {0.f, 0.f, 0.f, 0.f};
#pragma unroll
        for (int i = 0; i < 8; i++) {
            float4 kk = *(const float4*)&k[(size_t)srcn * F + i * 16 + h4 * 4];
            sacc[i >> 1] += qf[i].x * kk.x + qf[i].y * kk.y + qf[i].z * kk.z + qf[i].w * kk.w;
        }
        // combine element subsets across the 4 lanes of this slot
#pragma unroll
        for (int hh = 0; hh < 4; hh++) {
            sacc[hh] += __shfl_xor(sacc[hh], 1);
            sacc[hh] += __shfl_xor(sacc[hh], 2);
        }
        float s = h4 == 0 ? sacc[0] : h4 == 1 ? sacc[1] : h4 == 2 ? sacc[2] : sacc[3];
        if (mye >= deg) s = -INFINITY;

        // chunk max per head (reduce over slots)
        float cm = s;
        cm = fmaxf(cm, __shfl_xor(cm, 4));
        cm = fmaxf(cm, __shfl_xor(cm, 8));
        cm = fmaxf(cm, __shfl_xor(cm, 16));
        cm = fmaxf(cm, __shfl_xor(cm, 32));

        float nm_sc = fmaxf(m_sc, cm);
        float cm_ag = __shfl(cm, hagg);       // lane 'hagg' holds head hagg's chunk max
        float nm_ag = fmaxf(m_ag, cm_ag);

        float p = __expf(s - nm_sc);          // 0 for padded slots
        float psum = p;
        psum += __shfl_xor(psum, 4);
        psum += __shfl_xor(psum, 8);
        psum += __shfl_xor(psum, 16);
        psum += __shfl_xor(psum, 32);

        float scale = __expf(m_ag - nm_ag);   // first chunk: exp(-inf)=0, safe
        den = den * scale + __shfl(psum, hagg);
        accA.x *= scale; accA.y *= scale;
        accB.x *= scale; accB.y *= scale;

#pragma unroll 4
        for (int j = 0; j < nj; j++) {
            float pj = __shfl(p, (j << 2) | hagg);
            int sj = __shfl(srcn, j << 2);
            float2 v2 = *(const float2*)&v[(size_t)sj * F + lane * 2];
            if (j & 1) { accB.x += pj * v2.x; accB.y += pj * v2.y; }
            else       { accA.x += pj * v2.x; accA.y += pj * v2.y; }
        }
        m_sc = nm_sc;
        m_ag = nm_ag;
    }
    float inv = (den > 0.f) ? 1.f / den : 0.f;   // deg==0 -> zeros (ref: agg=0, out=bo)
    *(float2*)&agg[(size_t)n * F + lane * 2] =
        make_float2((accA.x + accB.x) * inv, (accA.y + accB.y) * inv);
}

// ---------------- launch ----------------
extern "C" void kernel_launch(void* const* d_in, const int* in_sizes, int n_in,
                              void* d_out, int out_size, void* d_ws, size_t ws_size,
                              hipStream_t stream) {
    const float* x  = (const float*)d_in[0];
    const int*   ei = (const int*)d_in[1];
    const float* wq = (const float*)d_in[2];
    const float* bq = (const float*)d_in[3];
    const float* wk = (const float*)d_in[4];
    const float* bk = (const float*)d_in[5];
    const float* wv = (const float*)d_in[6];
    const float* bv = (const float*)d_in[7];
    const float* wo = (const float*)d_in[8];
    const float* bo = (const float*)d_in[9];
    float* out = (float*)d_out;

    int N = in_sizes[0] / F;
    int E = in_sizes[1] / 2;
    const int* srcs = ei;
    const int* tgts = ei + E;

    // Workspace budget check — if d_ws is smaller than we need, launching would
    // write out of bounds and can wedge the device (container death). Refuse
    // instead: validation fails cleanly and the bench harness survives.
    size_t need = (size_t)N * F * 4 * 4        // q, k, v, agg
                + (size_t)(N + 1) * 4          // row_off
                + (size_t)N * 4 * 2            // next_, cnt
                + (size_t)E * 4;               // csr_src
    if (ws_size < need) return;

    char* wsp = (char*)d_ws;
    float* q   = (float*)wsp; wsp += (size_t)N * F * 4;
    float* k   = (float*)wsp; wsp += (size_t)N * F * 4;
    float* v   = (float*)wsp; wsp += (size_t)N * F * 4;
    float* agg = (float*)wsp; wsp += (size_t)N * F * 4;
    int* row_off = (int*)wsp; wsp += (size_t)(N + 1) * 4;
    int* next_   = (int*)wsp; wsp += (size_t)N * 4;
    int* cnt     = (int*)wsp; wsp += (size_t)N * 4;
    int* csr_src = (int*)wsp; wsp += (size_t)E * 4;

    hipMemsetAsync(cnt, 0, (size_t)N * 4, stream);
    hist_kernel<<<(E + 255) / 256, 256, 0, stream>>>(tgts, cnt, E);
    scan_kernel<<<1, 1024, 0, stream>>>(cnt, row_off, next_, N);
    scatter_kernel<<<(E + 255) / 256, 256, 0, stream>>>(srcs, tgts, next_, csr_src, E);
    qkv_kernel<<<dim3(512, 3), 256, 0, stream>>>(x, wq, bq, wk, bk, wv, bv, q, k, v, N);
    edge_attn_kernel<<<(N + 3) / 4, 256, 0, stream>>>(q, k, v, row_off, csr_src, agg, N);
    outproj_kernel<<<512, 256, 0, stream>>>(agg, wo, bo, out, N);
}